// Round 2
// baseline (401.771 us; speedup 1.0000x reference)
//
#include <hip/hip_runtime.h>

// loss = sum_{b,i,j} exp(-(g0^2/(2 s0^2) + g1^2/(2 s1^2))) * (z2[i]+z2[j]-2*zi.zj) / (B*T^2)
// Memory-bound on gt_dT (256 MB). Strategy:
//   prep:  z fp32 -> bf16 (4 MB, L2-resident) + row norms z2, zero out.
//   main:  sync-free, LDS-free. Per wave: 32x32 Gram in registers via
//          mfma_f32_16x16x32_bf16 (frags loaded straight from global bf16 z),
//          then stream gt with lanes mapped to the MFMA C/D layout
//          (col = lane&15, row = (lane>>4)*4 + reg  [verified round 1]).

#define T_DIM 2048
#define D_DIM 128
#define B_DIM 8
#define NTHREADS 256

typedef short s16x8 __attribute__((ext_vector_type(8)));
typedef float f32x4 __attribute__((ext_vector_type(4)));

__device__ __forceinline__ unsigned short f2bf(float x) {
    unsigned int u = __float_as_uint(x);
    u += 0x7fffu + ((u >> 16) & 1u);   // round-to-nearest-even
    return (unsigned short)(u >> 16);
}

__global__ __launch_bounds__(NTHREADS)
void patch_prep(const float* __restrict__ z, unsigned short* __restrict__ zbf,
                float* __restrict__ z2, float* __restrict__ out) {
    if (blockIdx.x == 0 && threadIdx.x == 0) out[0] = 0.0f;
    const int row = blockIdx.x * 8 + (threadIdx.x >> 5);   // 8 rows / block
    const int c4  = threadIdx.x & 31;                      // 32 float4 per row
    float4 v = ((const float4*)(z + (size_t)row * D_DIM))[c4];
    ushort4 p;
    p.x = f2bf(v.x); p.y = f2bf(v.y); p.z = f2bf(v.z); p.w = f2bf(v.w);
    ((ushort4*)(zbf + (size_t)row * D_DIM))[c4] = p;
    float s = v.x*v.x + v.y*v.y + v.z*v.z + v.w*v.w;
    #pragma unroll
    for (int m = 16; m >= 1; m >>= 1) s += __shfl_xor(s, m);
    if (c4 == 0) z2[row] = s;
}

__global__ __launch_bounds__(NTHREADS)
void patch_loss_main(const unsigned short* __restrict__ zbf,
                     const float* __restrict__ z2,
                     const float* __restrict__ gt,
                     const float* __restrict__ sigma,
                     float* __restrict__ out) {
    __shared__ float red[4];
    const int tid  = threadIdx.x;
    const int wave = tid >> 6;
    const int lane = tid & 63;
    const int c = lane & 15;     // fragment col (A/B row index, C/D col)
    const int q = lane >> 4;     // k-group for A/B, row-group for C/D

    const int b  = blockIdx.z;
    const int i0 = blockIdx.y * 64 + (wave >> 1) * 32;   // wave's 32x32 patch
    const int j0 = blockIdx.x * 64 + (wave & 1) * 32;

    const float s0 = sigma[0], s1 = sigma[1];
    const float a0 = 0.5f / (s0 * s0);
    const float a1 = 0.5f / (s1 * s1);

    const unsigned short* zi = zbf + ((size_t)b * T_DIM + i0) * D_DIM;
    const unsigned short* zj = zbf + ((size_t)b * T_DIM + j0) * D_DIM;

    // ---- Gram: 2x2 fragments of 16x16, K = 128 = 4*32, frags direct from L2 ----
    f32x4 acc[2][2] = {};
    #pragma unroll
    for (int kk = 0; kk < 4; ++kk) {
        const int co = kk * 32 + q * 8;
        s16x8 fa0 = *(const s16x8*)(zi + (size_t)(c)      * D_DIM + co);
        s16x8 fa1 = *(const s16x8*)(zi + (size_t)(16 + c) * D_DIM + co);
        s16x8 fb0 = *(const s16x8*)(zj + (size_t)(c)      * D_DIM + co);
        s16x8 fb1 = *(const s16x8*)(zj + (size_t)(16 + c) * D_DIM + co);
        acc[0][0] = __builtin_amdgcn_mfma_f32_16x16x32_bf16(fa0, fb0, acc[0][0], 0, 0, 0);
        acc[0][1] = __builtin_amdgcn_mfma_f32_16x16x32_bf16(fa0, fb1, acc[0][1], 0, 0, 0);
        acc[1][0] = __builtin_amdgcn_mfma_f32_16x16x32_bf16(fa1, fb0, acc[1][0], 0, 0, 0);
        acc[1][1] = __builtin_amdgcn_mfma_f32_16x16x32_bf16(fa1, fb1, acc[1][1], 0, 0, 0);
    }

    const float z2j0 = z2[(size_t)b * T_DIM + j0 + c];
    const float z2j1 = z2[(size_t)b * T_DIM + j0 + 16 + c];

    // ---- stream gt at the acc layout: 16 independent float2 loads / lane ----
    float facc = 0.0f;
    #pragma unroll
    for (int fi = 0; fi < 2; ++fi) {
        #pragma unroll
        for (int r = 0; r < 4; ++r) {
            const int i = i0 + fi * 16 + q * 4 + r;           // C/D row mapping
            const float zzi = z2[(size_t)b * T_DIM + i];      // broadcast (16-lane groups)
            const float* grow = gt + ((size_t)b * T_DIM + i) * (2 * T_DIM);
            #pragma unroll
            for (int fj = 0; fj < 2; ++fj) {
                const int j = j0 + fj * 16 + c;
                float2 g = *(const float2*)(grow + (size_t)j * 2);
                float t = g.x * g.x * a0 + g.y * g.y * a1;
                float w = __expf(-t);
                float d = zzi + (fj ? z2j1 : z2j0) - 2.0f * acc[fi][fj][r];
                facc += w * d;
            }
        }
    }

    // ---- reduce + atomic ----
    #pragma unroll
    for (int m = 32; m >= 1; m >>= 1) facc += __shfl_xor(facc, m);
    if (lane == 0) red[wave] = facc;
    __syncthreads();
    if (tid == 0) {
        const float scale = 1.0f / ((float)B_DIM * (float)T_DIM * (float)T_DIM);
        atomicAdd(out, (red[0] + red[1] + red[2] + red[3]) * scale);
    }
}

extern "C" void kernel_launch(void* const* d_in, const int* in_sizes, int n_in,
                              void* d_out, int out_size, void* d_ws, size_t ws_size,
                              hipStream_t stream) {
    const float* z     = (const float*)d_in[0];
    const float* gt    = (const float*)d_in[1];
    const float* sigma = (const float*)d_in[2];
    float* out = (float*)d_out;

    unsigned short* zbf = (unsigned short*)d_ws;                          // 4 MB
    float* z2 = (float*)((char*)d_ws + (size_t)B_DIM * T_DIM * D_DIM * 2); // 64 KB

    patch_prep<<<(B_DIM * T_DIM) / 8, NTHREADS, 0, stream>>>(z, zbf, z2, out);
    dim3 grid(T_DIM / 64, T_DIM / 64, B_DIM);
    patch_loss_main<<<grid, NTHREADS, 0, stream>>>(zbf, z2, gt, sigma, out);
}